// Round 8
// baseline (433.777 us; speedup 1.0000x reference)
//
#include <hip/hip_runtime.h>
#include <math.h>

// B=4, S=1024, D=1024, H=16, KVH=4, HD=64, HIDDEN=1024, BLK=8
#define SEQ 1024
#define DIM 1024

using short8 = __attribute__((ext_vector_type(8))) short;
using f32x4  = __attribute__((ext_vector_type(4))) float;

__device__ __forceinline__ unsigned short f2bf(float f) {
  unsigned int u = __float_as_uint(f);
  u = (u + 0x7FFFu + ((u >> 16) & 1u)) >> 16;
  return (unsigned short)u;
}
__device__ __forceinline__ float bf2f(unsigned short h) {
  return __uint_as_float(((unsigned int)h) << 16);
}
__device__ __forceinline__ void load16_lds(const unsigned short* g, unsigned short* l) {
  __builtin_amdgcn_global_load_lds((const __attribute__((address_space(1))) void*)g,
                                   (__attribute__((address_space(3))) void*)l, 16, 0, 0);
}

// ---------------- weight cast (f32 -> bf16), 9 regions ----------------
// ilv: 0 flat; 1/2 row-interleave (dst row = src_row*2 + ilv-1) for fused swiglu.
struct CastArgs {
  const float* src[9];
  unsigned short* dst[9];
  int n[9];
  int ilv[9];
};
__global__ __launch_bounds__(256) void cast_weights(CastArgs a) {
  int r = blockIdx.y;
  int i4 = (blockIdx.x * 256 + threadIdx.x) * 4;
  if (i4 >= a.n[r]) return;
  const float4 v = *(const float4*)(a.src[r] + i4);
  ushort4 o;
  o.x = f2bf(v.x); o.y = f2bf(v.y); o.z = f2bf(v.z); o.w = f2bf(v.w);
  size_t di = i4;
  if (a.ilv[r]) di = (size_t)((i4 >> 10) * 2 + (a.ilv[r] - 1)) * 1024 + (i4 & 1023);
  *(ushort4*)(a.dst[r] + di) = o;
}

// ---------------- silu(vec) -> bf16 ----------------
__global__ __launch_bounds__(256) void silu_cast(const float* __restrict__ v,
                                                 unsigned short* __restrict__ o, int n) {
  int i4 = (blockIdx.x * 256 + threadIdx.x) * 4;
  if (i4 >= n) return;
  float4 x = *(const float4*)(v + i4);
  ushort4 r;
  r.x = f2bf(x.x / (1.0f + expf(-x.x)));
  r.y = f2bf(x.y / (1.0f + expf(-x.y)));
  r.z = f2bf(x.z / (1.0f + expf(-x.z)));
  r.w = f2bf(x.w / (1.0f + expf(-x.w)));
  *(ushort4*)(o + i4) = r;
}

// ---------------- MFMA GEMM: C[M,N] = A[M,K] @ W[N,K]^T ----------------
// 128x64 block tile, 4 waves 2x2 (wave tile 64x32), BK=64.
// R8 restructure: A is streamed GLOBAL->VGPR fragments (b128 per lane; L1 holds the
// 8KB wave strip) -- no sA, ds_reads drop 12->4 per k-iter (R7 was LDS-read-bound at
// ~1150 cyc/CU-iter vs 155 cyc MFMA). Only W staged in LDS (dbuf, XOR-swizzled
// source); the barrier-coupled vmcnt drain now covers just 2 small W loads.
// A loads 2-deep pipelined (afE/afO) so they land under a full compute.
// EPI: 0 QKV(+RoPE)->bf16[N=1536]  1 +dual-bias->f32 (mod, N=6144)
//      2 x+gate*acc->f32 (h)       3 fused swiglu (interleaved)->bf16 g[.,1024]
//      4 h+gate*acc->f32 (final)
template<int EPI>
__global__ __launch_bounds__(256) void mfma_gemm(
    const unsigned short* __restrict__ A, const unsigned short* __restrict__ W,
    int M, int N, int K,
    float* __restrict__ outF, unsigned short* __restrict__ outBF,
    const float* __restrict__ aux1,   // bias1 / xres / hres
    const float* __restrict__ aux2,   // bias2 / mod-gate base (stride 6144)
    const float* __restrict__ fc, const float* __restrict__ fs)
{
  __shared__ unsigned short sB[2][64 * 64];   // 8 KB each
  const int tid = threadIdx.x;
  const int lane = tid & 63;
  const int wv = tid >> 6;
  const int wr = wv >> 1;           // row half (64 rows)
  const int wc = wv & 1;            // col half (32 cols)
  const int rowBlk = blockIdx.y * 128;
  const int colBlk = blockIdx.x * 64;
  const int q = lane >> 4;          // quad
  const int cl = lane & 15;

  f32x4 acc[4][2] = {};

  // per-lane A fragment base pointers (row fixed, k advances)
  const unsigned short* Abase[4];
#pragma unroll
  for (int t = 0; t < 4; ++t)
    Abase[t] = A + (size_t)(rowBlk + wr * 64 + t * 16 + cl) * K + q * 8;

  auto stageB = [&](int bf, int k0) {
#pragma unroll
    for (int j = 0; j < 2; ++j) {
      int slot = j * 256 + tid;
      int row = slot >> 3;
      int cg = (slot & 7) ^ (row & 7);
      load16_lds(W + (size_t)(colBlk + row) * K + k0 + cg * 8, &sB[bf][slot * 8]);
    }
  };

  short8 afE[4][2], afO[4][2];
#define LOADA(dst, k0v)                                        \
  _Pragma("unroll") for (int t = 0; t < 4; ++t)                \
    _Pragma("unroll") for (int s = 0; s < 2; ++s)              \
      dst[t][s] = *(const short8*)(Abase[t] + (k0v) + s * 32);

#define COMPUTE(af, bf)                                                          \
  {                                                                              \
    short8 bfr[2][2];                                                            \
    _Pragma("unroll") for (int t = 0; t < 2; ++t) {                              \
      int rowb = wc * 32 + t * 16 + cl;                                          \
      _Pragma("unroll") for (int s = 0; s < 2; ++s)                              \
        bfr[t][s] = *(const short8*)&sB[bf][rowb * 64 + (((s * 4 + q) ^ (cl & 7)) * 8)]; \
    }                                                                            \
    _Pragma("unroll") for (int s = 0; s < 2; ++s)                                \
      _Pragma("unroll") for (int tm = 0; tm < 4; ++tm)                           \
        _Pragma("unroll") for (int tn = 0; tn < 2; ++tn)                         \
          acc[tm][tn] = __builtin_amdgcn_mfma_f32_16x16x32_bf16(af[tm][s], bfr[tn][s], acc[tm][tn], 0, 0, 0); \
  }

  stageB(0, 0);
  LOADA(afE, 0);
  for (int k0 = 0; k0 < K; k0 += 128) {
    __syncthreads();                 // sB[0]+afE landed (issued a full compute ago)
    stageB(1, k0 + 64);
    LOADA(afO, k0 + 64);
    COMPUTE(afE, 0);
    __syncthreads();                 // sB[1]+afO landed
    if (k0 + 128 < K) {
      stageB(0, k0 + 128);
      LOADA(afE, k0 + 128);
    }
    COMPUTE(afO, 1);
  }

  // epilogue: C/D layout col=lane&15, row=quad*4+reg (verified m89/m91)
#pragma unroll
  for (int tm = 0; tm < 4; ++tm) {
#pragma unroll
    for (int tn = 0; tn < 2; ++tn) {
      const int col = colBlk + wc * 32 + tn * 16 + cl;
#pragma unroll
      for (int r = 0; r < 4; ++r) {
        const int row = rowBlk + wr * 64 + tm * 16 + q * 4 + r;
        float v = acc[tm][tn][r];
        if constexpr (EPI == 0) {
          float other = __shfl_xor(v, 1);   // partner col (col^1), same row
          if (col < 1280) {                 // Q and K get RoPE
            int s = row & (SEQ - 1);
            int t = (col & 63) >> 1;
            float cv = fc[s * 32 + t], sv = fs[s * 32 + t];
            v = ((col & 1) == 0) ? (v * cv - other * sv) : (other * sv + v * cv);
          }
          outBF[(size_t)row * N + col] = f2bf(v);
        } else if constexpr (EPI == 1) {
          float bb = (col < 3072) ? aux1[col] : aux2[col - 3072];
          outF[(size_t)row * N + col] = v + bb;
        } else if constexpr (EPI == 2 || EPI == 4) {
          int vr = (row >> 10) * 128 + ((row & (SEQ - 1)) >> 3);
          outF[(size_t)row * N + col] =
              aux1[(size_t)row * N + col] + aux2[(size_t)vr * 6144 + col] * v;
        } else if constexpr (EPI == 3) {
          float other = __shfl_xor(v, 1);   // odd col = u3
          if ((col & 1) == 0) {
            float g = v / (1.0f + expf(-v)) * other;
            outBF[(size_t)row * 1024 + (col >> 1)] = f2bf(g);
          }
        }
      }
    }
  }
}

// ---------------- rmsnorm + modulation -> bf16 ----------------
__global__ __launch_bounds__(256) void rms_mod(
    const float* __restrict__ X, const float* __restrict__ w,
    const float* __restrict__ mod, int off, unsigned short* __restrict__ out)
{
  const int r = blockIdx.x;
  const int b = r >> 10, s = r & (SEQ - 1);
  const int vr = b * 128 + (s >> 3);
  const size_t base = (size_t)r * DIM;
  float v[4];
  float ss = 0.f;
#pragma unroll
  for (int p = 0; p < 4; ++p) {
    int c = threadIdx.x + p * 256;
    v[p] = X[base + c];
    ss += v[p] * v[p];
  }
#pragma unroll
  for (int o = 1; o < 64; o <<= 1) ss += __shfl_xor(ss, o);
  __shared__ float red[4];
  int lane = threadIdx.x & 63, wvv = threadIdx.x >> 6;
  if (lane == 0) red[wvv] = ss;
  __syncthreads();
  float total = red[0] + red[1] + red[2] + red[3];
  float rn = rsqrtf(total * (1.0f / 1024.0f) + 1e-6f);
  const float* mrow = mod + (size_t)vr * 6144 + off;
#pragma unroll
  for (int p = 0; p < 4; ++p) {
    int c = threadIdx.x + p * 256;
    out[base + c] = f2bf(v[p] * rn * w[c] * (1.0f + mrow[1024 + c]) + mrow[c]);
  }
}

// ---------------- MFMA flash block-causal attention (balanced + prefetch) ----------------
// QKV packed [4096][1536] bf16: q 0..1023, k 1024..1279, v 1280..1535
// Grid 512: (b,h,qpair); q-tiles {pr, 15-pr} -> 17 KV iters/block.
// R8: next iter's K/V global reads prefetched into VGPRs right after the staging
// barrier, so their ~900-cyc latency lands under the ~1500-cyc compute.
__global__ __launch_bounds__(256) void attn_mfma(
    const unsigned short* __restrict__ QKV, unsigned short* __restrict__ O)
{
  const int bid = blockIdx.x;
  const int pr = bid & 7;
  const int h = (bid >> 3) & 15;
  const int b = bid >> 7;
  const int kvh = h >> 2;
  __shared__ unsigned short sK[64 * 64];      // [key][d], d XOR-swizzled by (key&7)*8
  __shared__ unsigned short sVt[64 * 72];     // [d][key], +8 pad
  __shared__ unsigned short sP[4][16 * 72];   // per-wave P strip
  const int tid = threadIdx.x;
  const int lane = tid & 63;
  const int w = tid >> 6;
  const int q = lane >> 4;
  const int cl = lane & 15;
  const float SCL = 0.125f * 1.44269504f;  // softmax in log2 domain

  // staging lane roles (fixed)
  const int krr = tid >> 3;             // K: row 0..31
  const int kd0 = (tid & 7) * 8;        // K: d offset
  const int vd  = tid & 63;             // V: d
  const int vkg = tid >> 6;             // V: key group

  short8 kreg[2];
  unsigned short vreg[2][8];

  auto loadKV = [&](int kt) {
    const size_t rb = (size_t)(b * SEQ + kt * 64);
#pragma unroll
    for (int ppp = 0; ppp < 2; ++ppp)
      kreg[ppp] = *(const short8*)(QKV + (rb + ppp * 32 + krr) * 1536 + 1024 + kvh * 64 + kd0);
#pragma unroll
    for (int ppp = 0; ppp < 2; ++ppp)
#pragma unroll
      for (int j = 0; j < 8; ++j)
        vreg[ppp][j] = QKV[(rb + ppp * 32 + vkg * 8 + j) * 1536 + 1280 + kvh * 64 + vd];
  };
  auto writeKV = [&]() {
#pragma unroll
    for (int ppp = 0; ppp < 2; ++ppp) {
      int key = ppp * 32 + krr;
      *(short8*)(sK + key * 64 + (kd0 ^ ((key & 7) * 8))) = kreg[ppp];
    }
#pragma unroll
    for (int ppp = 0; ppp < 2; ++ppp)
      *(short8*)(sVt + vd * 72 + ppp * 32 + vkg * 8) = *(const short8*)vreg[ppp];
  };

  for (int ph = 0; ph < 2; ++ph) {
    const int qt = ph ? (15 - pr) : pr;

    short8 qf[2];
    {
      const size_t qrow = (size_t)(b * SEQ + qt * 64 + w * 16 + cl) * 1536 + h * 64;
#pragma unroll
      for (int s = 0; s < 2; ++s)
        qf[s] = *(const short8*)(QKV + qrow + s * 32 + q * 8);
    }

    f32x4 accO[4] = {};
    float m_r[4], l_r[4];
#pragma unroll
    for (int r = 0; r < 4; ++r) { m_r[r] = -1e30f; l_r[r] = 0.f; }

    loadKV(0);
    for (int kt = 0; kt <= qt; ++kt) {
      __syncthreads();           // prior iter's LDS readers done
      writeKV();
      __syncthreads();           // K/V visible
      if (kt < qt) loadKV(kt + 1);   // block-uniform; lands under compute

      f32x4 accS[4] = {};
#pragma unroll
      for (int s = 0; s < 2; ++s) {
#pragma unroll
        for (int n = 0; n < 4; ++n) {
          int rowk = n * 16 + cl;
          short8 kf = *(const short8*)(sK + rowk * 64 + ((s * 32 + q * 8) ^ ((cl & 7) * 8)));
          accS[n] = __builtin_amdgcn_mfma_f32_16x16x32_bf16(qf[s], kf, accS[n], 0, 0, 0);
        }
      }

      float sv[4][4];
      const bool diag = (kt == qt);
      const int qblk = w * 2 + (q >> 1);
#pragma unroll
      for (int n = 0; n < 4; ++n) {
        const bool msk = diag && (n * 2 + (cl >> 3)) > qblk;
#pragma unroll
        for (int r = 0; r < 4; ++r)
          sv[n][r] = msk ? -1e30f : accS[n][r] * SCL;
      }

      float alpha[4];
#pragma unroll
      for (int r = 0; r < 4; ++r) {
        float vmax = fmaxf(fmaxf(sv[0][r], sv[1][r]), fmaxf(sv[2][r], sv[3][r]));
        vmax = fmaxf(vmax, __shfl_xor(vmax, 1));
        vmax = fmaxf(vmax, __shfl_xor(vmax, 2));
        vmax = fmaxf(vmax, __shfl_xor(vmax, 4));
        vmax = fmaxf(vmax, __shfl_xor(vmax, 8));
        float mnew = fmaxf(m_r[r], vmax);
        alpha[r] = exp2f(m_r[r] - mnew);
        float rs = 0.f;
#pragma unroll
        for (int n = 0; n < 4; ++n) {
          float pp = exp2f(sv[n][r] - mnew);
          sv[n][r] = pp;
          rs += pp;
        }
        rs += __shfl_xor(rs, 1);
        rs += __shfl_xor(rs, 2);
        rs += __shfl_xor(rs, 4);
        rs += __shfl_xor(rs, 8);
        l_r[r] = l_r[r] * alpha[r] + rs;
        m_r[r] = mnew;
      }

#pragma unroll
      for (int n = 0; n < 4; ++n)
#pragma unroll
        for (int r = 0; r < 4; ++r)
          sP[w][(q * 4 + r) * 72 + n * 16 + cl] = f2bf(sv[n][r]);

#pragma unroll
      for (int dn = 0; dn < 4; ++dn) {
        accO[dn][0] *= alpha[0];
        accO[dn][1] *= alpha[1];
        accO[dn][2] *= alpha[2];
        accO[dn][3] *= alpha[3];
      }

      short8 pf[2];
      pf[0] = *(const short8*)(&sP[w][cl * 72 + q * 8]);
      pf[1] = *(const short8*)(&sP[w][cl * 72 + 32 + q * 8]);
#pragma unroll
      for (int dn = 0; dn < 4; ++dn) {
#pragma unroll
        for (int s = 0; s < 2; ++s) {
          short8 vf = *(const short8*)(sVt + (dn * 16 + cl) * 72 + s * 32 + q * 8);
          accO[dn] = __builtin_amdgcn_mfma_f32_16x16x32_bf16(pf[s], vf, accO[dn], 0, 0, 0);
        }
      }
    }

    float invl[4];
#pragma unroll
    for (int r = 0; r < 4; ++r) invl[r] = 1.0f / l_r[r];
#pragma unroll
    for (int dn = 0; dn < 4; ++dn)
#pragma unroll
      for (int r = 0; r < 4; ++r) {
        int row = b * SEQ + qt * 64 + w * 16 + q * 4 + r;
        O[(size_t)row * DIM + h * 64 + dn * 16 + cl] = f2bf(accO[dn][r] * invl[r]);
      }
  }
}

extern "C" void kernel_launch(void* const* d_in, const int* in_sizes, int n_in,
                              void* d_out, int out_size, void* d_ws, size_t ws_size,
                              hipStream_t stream)
{
  const float* x   = (const float*)d_in[0];
  const float* vec = (const float*)d_in[1];
  const float* wq  = (const float*)d_in[2];
  const float* wk  = (const float*)d_in[3];
  const float* wv  = (const float*)d_in[4];
  const float* wo  = (const float*)d_in[5];
  const float* w1  = (const float*)d_in[6];
  const float* w2  = (const float*)d_in[7];
  const float* w3  = (const float*)d_in[8];
  const float* maw = (const float*)d_in[9];
  const float* mab = (const float*)d_in[10];
  const float* mfw = (const float*)d_in[11];
  const float* mfb = (const float*)d_in[12];
  const float* n1w = (const float*)d_in[13];
  const float* n2w = (const float*)d_in[14];
  const float* fc  = (const float*)d_in[15];
  const float* fs  = (const float*)d_in[16];

  char* p = (char*)d_ws;
  auto takeU = [&](size_t elems) { unsigned short* r = (unsigned short*)p; p += elems * 2; return r; };
  auto takeF = [&](size_t elems) { float* r = (float*)p; p += elems * 4; return r; };

  unsigned short* WQKV = takeU((size_t)1536 * 1024);
  unsigned short* WOb  = takeU((size_t)1024 * 1024);
  unsigned short* W13  = takeU((size_t)2048 * 1024);   // row-interleaved w1/w3
  unsigned short* W2b  = takeU((size_t)1024 * 1024);
  unsigned short* WM   = takeU((size_t)6144 * 1024);   // [mod_attn_w | mod_ffn_w]
  unsigned short* SVEC = takeU((size_t)512 * 1024);
  float* MOD  = takeF((size_t)512 * 6144);             // [sh_a|sc_a|gt_a|sh_f|sc_f|gt_f]
  float* H    = takeF((size_t)4096 * 1024);
  unsigned short* XNb  = takeU((size_t)4096 * 1024);
  unsigned short* QKVb = takeU((size_t)4096 * 1536);
  unsigned short* AOb  = takeU((size_t)4096 * 1024);
  unsigned short* HNb  = takeU((size_t)4096 * 1024);
  unsigned short* Gb  = AOb;   // alias: AO dead after WO gemm

  dim3 blk(256);

  CastArgs ca;
  ca.src[0] = wq;  ca.dst[0] = WQKV;                    ca.n[0] = 1024 * 1024; ca.ilv[0] = 0;
  ca.src[1] = wk;  ca.dst[1] = WQKV + 1024 * 1024;      ca.n[1] = 256 * 1024;  ca.ilv[1] = 0;
  ca.src[2] = wv;  ca.dst[2] = WQKV + 1280 * 1024;      ca.n[2] = 256 * 1024;  ca.ilv[2] = 0;
  ca.src[3] = wo;  ca.dst[3] = WOb;                     ca.n[3] = 1024 * 1024; ca.ilv[3] = 0;
  ca.src[4] = w1;  ca.dst[4] = W13;                     ca.n[4] = 1024 * 1024; ca.ilv[4] = 1;
  ca.src[5] = w3;  ca.dst[5] = W13;                     ca.n[5] = 1024 * 1024; ca.ilv[5] = 2;
  ca.src[6] = w2;  ca.dst[6] = W2b;                     ca.n[6] = 1024 * 1024; ca.ilv[6] = 0;
  ca.src[7] = maw; ca.dst[7] = WM;                      ca.n[7] = 3072 * 1024; ca.ilv[7] = 0;
  ca.src[8] = mfw; ca.dst[8] = WM + (size_t)3072 * 1024; ca.n[8] = 3072 * 1024; ca.ilv[8] = 0;
  cast_weights<<<dim3(3072, 9), blk, 0, stream>>>(ca);

  silu_cast<<<512, blk, 0, stream>>>(vec, SVEC, 512 * 1024);

  // merged modulation GEMM -> f32 [512, 6144]  (grid 384)
  mfma_gemm<1><<<dim3(96, 4), blk, 0, stream>>>(SVEC, WM, 512, 6144, 1024,
      MOD, nullptr, mab, mfb, nullptr, nullptr);

  rms_mod<<<4096, blk, 0, stream>>>(x, n1w, MOD, 0, XNb);

  // fused QKV GEMM + RoPE -> packed bf16 [4096,1536]  (grid 768)
  mfma_gemm<0><<<dim3(24, 32), blk, 0, stream>>>(XNb, WQKV, 4096, 1536, 1024,
      nullptr, QKVb, nullptr, nullptr, fc, fs);

  attn_mfma<<<512, blk, 0, stream>>>(QKVb, AOb);

  // h = x + gate_a * (AO @ wo^T) -> f32  (grid 512)
  mfma_gemm<2><<<dim3(16, 32), blk, 0, stream>>>(AOb, WOb, 4096, 1024, 1024,
      H, nullptr, x, MOD + 2048, nullptr, nullptr);

  rms_mod<<<4096, blk, 0, stream>>>(H, n2w, MOD, 3072, HNb);

  // g = silu(hn@w1^T)*(hn@w3^T) fused epilogue -> bf16 [4096,1024]  (grid 1024)
  mfma_gemm<3><<<dim3(32, 32), blk, 0, stream>>>(HNb, W13, 4096, 2048, 1024,
      nullptr, Gb, nullptr, nullptr, nullptr, nullptr);

  // out = h + gate_f * (g @ w2^T) -> f32  (grid 512)
  mfma_gemm<4><<<dim3(16, 32), blk, 0, stream>>>(Gb, W2b, 4096, 1024, 1024,
      (float*)d_out, nullptr, H, MOD + 5120, nullptr, nullptr);
}